// Round 3
// baseline (10283.838 us; speedup 1.0000x reference)
//
#include <hip/hip_runtime.h>
#include <cstddef>
#include <cstdint>

#define S_LEN 64
#define BATCH 128
#define T_LEN 32
#define E_DIM 256
#define VOCAB 32000
#define XDIM 1792
#define MPAD 4096      // padded M for output GEMM (3968 -> 4096)
#define ENC_NB 48
#define DEC_NB 64

typedef unsigned short bfu;
typedef short short8 __attribute__((ext_vector_type(8)));
typedef float f32x4 __attribute__((ext_vector_type(4)));

__device__ __forceinline__ float sigm(float x) { return 1.f / (1.f + expf(-x)); }
__device__ __forceinline__ bfu f2b(float f) {
    unsigned int x = __float_as_uint(f);
    x += 0x7fffu + ((x >> 16) & 1u);
    return (bfu)(x >> 16);
}
__device__ __forceinline__ float b2f(bfu u) { return __uint_as_float(((unsigned)u) << 16); }
__device__ __forceinline__ f32x4 MFMA16(short8 a, short8 b, f32x4 c) {
    return __builtin_amdgcn_mfma_f32_16x16x32_bf16(a, b, c, 0, 0, 0);
}

#define GLDS(gsrc, ldst)                                                       \
    __builtin_amdgcn_global_load_lds(                                          \
        (const __attribute__((address_space(1))) void*)(gsrc),                 \
        (__attribute__((address_space(3))) void*)(ldst), 16, 0, 0)

// device-scope grid barrier: release-fence, arrive, relaxed spin, acquire-fence
#define GRIDBAR(barp, NB)                                                      \
    do {                                                                       \
        __builtin_amdgcn_fence(__ATOMIC_RELEASE, "agent");                     \
        __syncthreads();                                                       \
        target += (NB);                                                        \
        if (threadIdx.x == 0) {                                                \
            __hip_atomic_fetch_add(barp, 1u, __ATOMIC_RELEASE,                 \
                                   __HIP_MEMORY_SCOPE_AGENT);                  \
            while (__hip_atomic_load(barp, __ATOMIC_RELAXED,                   \
                                     __HIP_MEMORY_SCOPE_AGENT) < target)       \
                __builtin_amdgcn_s_sleep(2);                                   \
        }                                                                      \
        __syncthreads();                                                       \
        __builtin_amdgcn_fence(__ATOMIC_ACQUIRE, "agent");                     \
    } while (0)

// ---------------------------------------------------------------- utilities
__global__ void zero_kernel(float* __restrict__ p, int n) {
    int i = blockIdx.x * 256 + threadIdx.x;
    if (i < n) p[i] = 0.f;
}

__global__ void conv_f2b(const float* __restrict__ in, bfu* __restrict__ out, int n4) {
    int i = blockIdx.x * 256 + threadIdx.x;
    if (i >= n4) return;
    float4 v = ((const float4*)in)[i];
    ushort4 o;
    o.x = f2b(v.x); o.y = f2b(v.y); o.z = f2b(v.z); o.w = f2b(v.w);
    ((ushort4*)out)[i] = o;
}

__global__ void gather_emb(const float* __restrict__ table, const int* __restrict__ idx,
                           bfu* __restrict__ out, int total) {
    int i = blockIdx.x * 256 + threadIdx.x;
    if (i >= total) return;
    int row = i >> 8, k = i & 255;
    out[i] = f2b(table[(size_t)idx[row] * E_DIM + k]);
}

__global__ void gather_trg(const float* __restrict__ table, const int* __restrict__ trg,
                           bfu* __restrict__ Xb, int total) {
    int i = blockIdx.x * 256 + threadIdx.x;
    if (i >= total) return;
    int row = i >> 8, k = i & 255;
    Xb[(size_t)row * XDIM + 1536 + k] = f2b(table[(size_t)trg[row] * E_DIM + k]);
}

// ----------------------------------------------- generic bf16 MFMA GEMM (NT)
// (verified round 2) BM=BN=128, BK=32; 256 thr = 4 waves 2x2, wave tile 64x64
__global__ __launch_bounds__(256) void gemm_bf16(
    const bfu* __restrict__ A0, int lda0, const bfu* __restrict__ W0, int ldw0,
    float* __restrict__ C0, int ldc0, const float* __restrict__ bias0, int K0,
    const bfu* __restrict__ A1, int lda1, const bfu* __restrict__ W1, int ldw1,
    float* __restrict__ C1, int ldc1, const float* __restrict__ bias1, int K1,
    int act, bfu* __restrict__ Cb0)
{
    const int z = blockIdx.z;
    const bfu* A = z ? A1 : A0;
    const bfu* W = z ? W1 : W0;
    float*     C = z ? C1 : C0;
    const float* bias = z ? bias1 : bias0;
    bfu*       Cb = z ? nullptr : Cb0;
    const int lda = z ? lda1 : lda0;
    const int ldw = z ? ldw1 : ldw0;
    const int ldc = z ? ldc1 : ldc0;
    const int K   = z ? K1 : K0;

    __shared__ short lds[2][2][4096];
    const int tid  = threadIdx.x;
    const int wid  = tid >> 6, lane = tid & 63;
    const int l15  = lane & 15, lk = lane >> 4;
    const int wr   = (wid >> 1) * 64, wc = (wid & 1) * 64;
    const size_t row0 = (size_t)blockIdx.y * 128;
    const size_t col0 = (size_t)blockIdx.x * 128;

    const int c0 = tid, c1 = tid + 256;
    const int r0 = c0 & 127, kc0 = c0 >> 7;
    const int r1 = c1 & 127, kc1 = c1 >> 7;
    const int sb0 = (wid * 64) * 16;
    const int sb1 = (wid * 64 + 256) * 16;

    f32x4 acc[4][4];
#pragma unroll
    for (int m = 0; m < 4; ++m)
#pragma unroll
        for (int n = 0; n < 4; ++n) acc[m][n] = (f32x4){0.f, 0.f, 0.f, 0.f};

    auto stage = [&](int buf, int kt) {
        char* ba = (char*)&lds[buf][0][0];
        char* bb = (char*)&lds[buf][1][0];
        GLDS(A + (row0 + r0) * (size_t)lda + kt + kc0 * 8, ba + sb0);
        GLDS(A + (row0 + r1) * (size_t)lda + kt + kc1 * 8, ba + sb1);
        GLDS(W + (col0 + r0) * (size_t)ldw + kt + kc0 * 8, bb + sb0);
        GLDS(W + (col0 + r1) * (size_t)ldw + kt + kc1 * 8, bb + sb1);
    };

    stage(0, 0);
    __syncthreads();
    const int nk = K >> 5;
    for (int t = 0; t < nk; ++t) {
        const int buf = t & 1;
        if (t + 1 < nk) stage(buf ^ 1, (t + 1) << 5);
        short8 af[4], bf_[4];
#pragma unroll
        for (int m = 0; m < 4; ++m)
            af[m] = *(const short8*)&lds[buf][0][lk * 1024 + (wr + m * 16 + l15) * 8];
#pragma unroll
        for (int n = 0; n < 4; ++n)
            bf_[n] = *(const short8*)&lds[buf][1][lk * 1024 + (wc + n * 16 + l15) * 8];
#pragma unroll
        for (int m = 0; m < 4; ++m)
#pragma unroll
            for (int n = 0; n < 4; ++n)
                acc[m][n] = MFMA16(af[m], bf_[n], acc[m][n]);
        __syncthreads();
    }

    float bv[4];
#pragma unroll
    for (int n = 0; n < 4; ++n)
        bv[n] = bias ? bias[col0 + wc + n * 16 + l15] : 0.f;
    const size_t crow = row0 + wr + lk * 4;
#pragma unroll
    for (int m = 0; m < 4; ++m) {
#pragma unroll
        for (int q = 0; q < 4; ++q) {
            const size_t r = crow + m * 16 + q;
            float* cp = C + r * ldc + col0 + wc + l15;
            bfu*   cb = Cb ? (Cb + r * ldc + col0 + wc + l15) : nullptr;
#pragma unroll
            for (int n = 0; n < 4; ++n) {
                float v = acc[m][n][q] + bv[n];
                if (act) v = tanhf(v);
                cp[n * 16] = v;
                if (Cb) cb[n * 16] = f2b(v);
            }
        }
    }
}

// ----------------------------------------------- big output GEMM, 256x256 tile
// C[3968][32000] = Xb[4096(pad)][1792] @ Wout[32000][1792]^T + b_out
// 512 thr = 8 waves (2 row x 4 col), wave tile 128x64, BK=32.
__global__ __launch_bounds__(512) void gemm_big(
    const bfu* __restrict__ A, const bfu* __restrict__ W,
    float* __restrict__ C, const float* __restrict__ bias)
{
    __shared__ short lds[2][2][8192];   // [buf][op][kc4*2048 + row*8]
    const int tid = threadIdx.x;
    const int wid = tid >> 6, lane = tid & 63;
    const int l15 = lane & 15, lk = lane >> 4;
    const int wr = (wid >> 2) * 128;
    const int wcc = (wid & 3) * 64;
    // bijective XCD swizzle: XCD k owns bx range -> W streamed ~once per XCD L2
    const int fid  = blockIdx.y * 125 + blockIdx.x;       // 2000 = 8*250
    const int fid2 = (fid & 7) * 250 + (fid >> 3);
    const int bx = fid2 / 16, by = fid2 % 16;
    const size_t row0 = (size_t)by * 256;
    const size_t col0 = (size_t)bx * 256;

    f32x4 acc[8][4];
#pragma unroll
    for (int m = 0; m < 8; ++m)
#pragma unroll
        for (int n = 0; n < 4; ++n) acc[m][n] = (f32x4){0.f, 0.f, 0.f, 0.f};

    auto stage = [&](int buf, int kt) {
        char* ba = (char*)&lds[buf][0][0];
        char* bb = (char*)&lds[buf][1][0];
#pragma unroll
        for (int it = 0; it < 2; ++it) {
            int c = it * 512 + tid;
            int kc = c >> 8, row = c & 255;
            int base = (it * 512 + wid * 64) * 16;
            GLDS(A + (row0 + row) * (size_t)XDIM + kt + kc * 8, ba + base);
            GLDS(W + (col0 + row) * (size_t)XDIM + kt + kc * 8, bb + base);
        }
    };

    stage(0, 0);
    __syncthreads();
    for (int t = 0; t < 56; ++t) {
        const int buf = t & 1;
        if (t < 55) stage(buf ^ 1, (t + 1) * 32);
        short8 af[8], bf_[4];
#pragma unroll
        for (int m = 0; m < 8; ++m)
            af[m] = *(const short8*)&lds[buf][0][lk * 2048 + (wr + m * 16 + l15) * 8];
#pragma unroll
        for (int n = 0; n < 4; ++n)
            bf_[n] = *(const short8*)&lds[buf][1][lk * 2048 + (wcc + n * 16 + l15) * 8];
#pragma unroll
        for (int m = 0; m < 8; ++m)
#pragma unroll
            for (int n = 0; n < 4; ++n)
                acc[m][n] = MFMA16(af[m], bf_[n], acc[m][n]);
        __syncthreads();
    }
    if (row0 + wr < 3968) {     // wave-uniform M-pad guard (3968 = 15.5*256)
        float bv[4];
#pragma unroll
        for (int n = 0; n < 4; ++n) bv[n] = bias[col0 + wcc + n * 16 + l15];
#pragma unroll
        for (int m = 0; m < 8; ++m) {
#pragma unroll
            for (int q = 0; q < 4; ++q) {
                const size_t r = row0 + wr + lk * 4 + m * 16 + q;
                float* cp = C + r * VOCAB + col0 + wcc + l15;
#pragma unroll
                for (int n = 0; n < 4; ++n) cp[n * 16] = acc[m][n][q] + bv[n];
            }
        }
    }
}

// ----------------------------------------------- persistent encoder (1 launch)
// 48 blocks: dir = blk/24, 64-col slice of 1536. Whh slice resident in LDS.
__global__ __launch_bounds__(256) void enc_persistent(
    const float* __restrict__ gi_f, const float* __restrict__ gi_b,
    const bfu* __restrict__ Whhf_b, const bfu* __restrict__ Whhb_b,
    const float* __restrict__ bhh_f, const float* __restrict__ bhh_b,
    float* __restrict__ hA, float* __restrict__ hB,
    bfu* __restrict__ hbA, bfu* __restrict__ hbB,
    float* __restrict__ gh, bfu* __restrict__ encbt,
    unsigned* __restrict__ bar)
{
    __shared__ short Wl[64 * 64 * 8];      // 64KB resident [kc64][row64][8]
    __shared__ short Al[2][4 * 128 * 8];   // 16KB A staging
    const int tid = threadIdx.x, blk = blockIdx.x;
    const int wid = tid >> 6, lane = tid & 63;
    const int l15 = lane & 15, lk = lane >> 4;
    const int wr = (wid >> 1) * 64, wcc = (wid & 1) * 32;
    const int dir = blk / 24, cs = (blk % 24) * 64;
    const bfu* Whh = dir ? Whhb_b : Whhf_b;
    const float* bhh = dir ? bhh_b : bhh_f;
    unsigned target = 0;
    {
        char* base = (char*)Wl;
#pragma unroll
        for (int it = 0; it < 16; ++it) {
            int c = it * 256 + tid;
            int kc = c >> 6, rw = c & 63;
            GLDS(Whh + (size_t)(cs + rw) * 512 + kc * 8, base + (it * 256 + wid * 64) * 16);
        }
        __syncthreads();
    }
    for (int s = 0; s < S_LEN; ++s) {
        const float* hin = (s & 1) ? hB : hA;
        float* hout = (s & 1) ? hA : hB;
        const bfu* hbin = (s & 1) ? hbB : hbA;
        bfu* hbout = (s & 1) ? hbA : hbB;
        // gh[dir][128][1536] cols cs..cs+63 = hbin(dir) @ Whh^T + bhh
        {
            f32x4 acc[4][2];
#pragma unroll
            for (int m = 0; m < 4; ++m) { acc[m][0] = (f32x4){0,0,0,0}; acc[m][1] = (f32x4){0,0,0,0}; }
            auto stageA = [&](int buf, int kt) {
                char* ba = (char*)&Al[buf][0];
#pragma unroll
                for (int it = 0; it < 2; ++it) {
                    int c = it * 256 + tid;
                    int kc = c >> 7, row = c & 127;
                    GLDS(hbin + (size_t)row * 1024 + dir * 512 + kt + kc * 8,
                         ba + (it * 256 + wid * 64) * 16);
                }
            };
            stageA(0, 0);
            __syncthreads();
            for (int kk = 0; kk < 16; ++kk) {
                int buf = kk & 1;
                if (kk < 15) stageA(buf ^ 1, (kk + 1) * 32);
                short8 b0 = *(const short8*)&Wl[(kk * 4 + lk) * 512 + (wcc + l15) * 8];
                short8 b1 = *(const short8*)&Wl[(kk * 4 + lk) * 512 + (wcc + 16 + l15) * 8];
#pragma unroll
                for (int m = 0; m < 4; ++m) {
                    short8 afr = *(const short8*)&Al[buf][lk * 1024 + (wr + m * 16 + l15) * 8];
                    acc[m][0] = MFMA16(afr, b0, acc[m][0]);
                    acc[m][1] = MFMA16(afr, b1, acc[m][1]);
                }
                __syncthreads();
            }
#pragma unroll
            for (int n = 0; n < 2; ++n) {
                int j = cs + wcc + n * 16 + l15;
                float bb = bhh[j];
#pragma unroll
                for (int m = 0; m < 4; ++m)
#pragma unroll
                    for (int q = 0; q < 4; ++q)
                        gh[((size_t)dir * 128 + (wr + lk * 4 + m * 16 + q)) * 1536 + j] =
                            acc[m][n][q] + bb;
            }
        }
        GRIDBAR(bar, ENC_NB);
        for (int i = blk * 256 + tid; i < 131072; i += ENC_NB * 256) {
            int b = i >> 10, rest = i & 1023, d2 = rest >> 9, u = rest & 511;
            int p = d2 ? (S_LEN - 1 - s) : s;
            const float* gip = (d2 ? gi_b : gi_f) + ((size_t)p * BATCH + b) * 1536;
            const float* ghp = gh + ((size_t)d2 * 128 + b) * 1536;
            float rr = sigm(gip[u] + ghp[u]);
            float zz = sigm(gip[512 + u] + ghp[512 + u]);
            float nn = tanhf(gip[1024 + u] + rr * ghp[1024 + u]);
            float h2 = (1.f - zz) * nn + zz * hin[(size_t)b * 1024 + d2 * 512 + u];
            hout[(size_t)b * 1024 + d2 * 512 + u] = h2;
            hbout[(size_t)b * 1024 + d2 * 512 + u] = f2b(h2);
            encbt[((size_t)b * S_LEN + p) * 1024 + d2 * 512 + u] = f2b(h2);
        }
        GRIDBAR(bar, ENC_NB);
    }
}

// ----------------------------------------------- persistent decoder (1 launch)
// 64 blocks. blk<16: hp cols (512); blk>=16: ghd+giw cols (1536). 4 phases/step.
__global__ __launch_bounds__(256) void dec_persistent(
    const float* __restrict__ gie, const bfu* __restrict__ Wattn_b,
    const bfu* __restrict__ Whhd_b, const bfu* __restrict__ Wihd_b,
    const float* __restrict__ bhh_d,
    const float* __restrict__ encp, const bfu* __restrict__ encbt,
    const float* __restrict__ v_attn, const int* __restrict__ src,
    float* __restrict__ hdA, float* __restrict__ hdB,
    bfu* __restrict__ hdbA, bfu* __restrict__ hdbB,
    float* __restrict__ hp, bfu* __restrict__ wbuf,
    float* __restrict__ ghd, float* __restrict__ giw,
    bfu* __restrict__ Xb, unsigned* __restrict__ bar)
{
    __shared__ short Wa[64 * 32 * 8];       // 32KB [kc64][32][8]
    __shared__ short Wc[128 * 32 * 8];      // 64KB [kc128][32][8]
    __shared__ short Al[2][4 * 128 * 8];    // 16KB
    __shared__ float vas[512];
    __shared__ float hps[512];
    __shared__ float sc[64];
    const int tid = threadIdx.x, blk = blockIdx.x;
    const int wid = tid >> 6, lane = tid & 63;
    const int l15 = lane & 15, lk = lane >> 4;
    const int wr = (wid >> 1) * 64, wcc = (wid & 1) * 16;
    const bool isGA = blk < 16;
    const int c0 = isGA ? blk * 32 : (blk - 16) * 32;
    unsigned target = 0;
    {
        char* base = (char*)Wa;
#pragma unroll
        for (int it = 0; it < 8; ++it) {
            int c = it * 256 + tid;
            int kc = c >> 5, rw = c & 31;
            const bfu* sp = isGA ? (Wattn_b + (size_t)(c0 + rw) * 1536 + kc * 8)
                                 : (Whhd_b + (size_t)(c0 + rw) * 512 + kc * 8);
            GLDS(sp, base + (it * 256 + wid * 64) * 16);
        }
        if (!isGA) {
            char* basec = (char*)Wc;
#pragma unroll
            for (int it = 0; it < 16; ++it) {
                int c = it * 256 + tid;
                int kc = c >> 5, rw = c & 31;
                GLDS(Wihd_b + (size_t)(c0 + rw) * 1280 + 256 + kc * 8,
                     basec + (it * 256 + wid * 64) * 16);
            }
        }
        for (int i = tid; i < 512; i += 256) vas[i] = v_attn[i];
        __syncthreads();
    }
    for (int t = 0; t < T_LEN - 1; ++t) {
        const float* hin = (t & 1) ? hdB : hdA;
        float* hout = (t & 1) ? hdA : hdB;
        const bfu* hbin = (t & 1) ? hdbB : hdbA;
        bfu* hbout = (t & 1) ? hdbA : hdbB;
        // -- Phase A: out[128][32] = hbin[128x512] @ Wa^T  (hp | ghd)
        {
            f32x4 acc[4];
#pragma unroll
            for (int m = 0; m < 4; ++m) acc[m] = (f32x4){0, 0, 0, 0};
            auto stageA = [&](int buf, int kt) {
                char* ba = (char*)&Al[buf][0];
#pragma unroll
                for (int it = 0; it < 2; ++it) {
                    int c = it * 256 + tid;
                    int kc = c >> 7, row = c & 127;
                    GLDS(hbin + (size_t)row * 512 + kt + kc * 8,
                         ba + (it * 256 + wid * 64) * 16);
                }
            };
            stageA(0, 0);
            __syncthreads();
            for (int kk = 0; kk < 16; ++kk) {
                int buf = kk & 1;
                if (kk < 15) stageA(buf ^ 1, (kk + 1) * 32);
                short8 bfr = *(const short8*)&Wa[(kk * 4 + lk) * 256 + (wcc + l15) * 8];
#pragma unroll
                for (int m = 0; m < 4; ++m) {
                    short8 afr = *(const short8*)&Al[buf][lk * 1024 + (wr + m * 16 + l15) * 8];
                    acc[m] = MFMA16(afr, bfr, acc[m]);
                }
                __syncthreads();
            }
            const int j = c0 + wcc + l15;
            if (isGA) {
#pragma unroll
                for (int m = 0; m < 4; ++m)
#pragma unroll
                    for (int q = 0; q < 4; ++q)
                        hp[(size_t)(wr + lk * 4 + m * 16 + q) * 512 + j] = acc[m][q];
            } else {
                float bb = bhh_d[j];
#pragma unroll
                for (int m = 0; m < 4; ++m)
#pragma unroll
                    for (int q = 0; q < 4; ++q)
                        ghd[(size_t)(wr + lk * 4 + m * 16 + q) * 1536 + j] = acc[m][q] + bb;
            }
        }
        GRIDBAR(bar, DEC_NB);
        // -- Phase B: attention, 2 batches per block
        for (int bi = 0; bi < 2; ++bi) {
            const int b = blk * 2 + bi;
            hps[tid] = hp[(size_t)b * 512 + tid];
            hps[tid + 256] = hp[(size_t)b * 512 + 256 + tid];
            __syncthreads();
            const int s = tid >> 2, l4 = tid & 3;
            const float* ep = encp + ((size_t)b * S_LEN + s) * 512;
            float part = 0.f;
#pragma unroll 4
            for (int d = l4; d < 512; d += 4) part += vas[d] * tanhf(ep[d] + hps[d]);
            part += __shfl_xor(part, 1);
            part += __shfl_xor(part, 2);
            if (l4 == 0) sc[s] = (src[s * BATCH + b] != 0) ? part : -1e10f;
            __syncthreads();
            if (tid < 64) {
                float x = sc[tid], mx = x;
                for (int o = 1; o < 64; o <<= 1) mx = fmaxf(mx, __shfl_xor(mx, o));
                float e = expf(x - mx), s2 = e;
                for (int o = 1; o < 64; o <<= 1) s2 += __shfl_xor(s2, o);
                sc[tid] = e / s2;
            }
            __syncthreads();
            const bfu* eb = encbt + (size_t)b * S_LEN * 1024;
            bfu* xw = Xb + ((size_t)t * BATCH + b) * XDIM + 512;
#pragma unroll
            for (int c = 0; c < 4; ++c) {
                int e = tid + 256 * c;
                float a2 = 0.f;
#pragma unroll 8
                for (int s2 = 0; s2 < S_LEN; ++s2) a2 += sc[s2] * b2f(eb[(size_t)s2 * 1024 + e]);
                wbuf[(size_t)b * 1024 + e] = f2b(a2);
                xw[e] = f2b(a2);
            }
            __syncthreads();
        }
        GRIDBAR(bar, DEC_NB);
        // -- Phase C: giw[128][1536] = wbuf[128x1024] @ Wc^T (GB blocks only)
        if (!isGA) {
            f32x4 acc[4];
#pragma unroll
            for (int m = 0; m < 4; ++m) acc[m] = (f32x4){0, 0, 0, 0};
            auto stageC = [&](int buf, int kt) {
                char* ba = (char*)&Al[buf][0];
#pragma unroll
                for (int it = 0; it < 2; ++it) {
                    int c = it * 256 + tid;
                    int kc = c >> 7, row = c & 127;
                    GLDS(wbuf + (size_t)row * 1024 + kt + kc * 8,
                         ba + (it * 256 + wid * 64) * 16);
                }
            };
            stageC(0, 0);
            __syncthreads();
            for (int kk = 0; kk < 32; ++kk) {
                int buf = kk & 1;
                if (kk < 31) stageC(buf ^ 1, (kk + 1) * 32);
                short8 bfr = *(const short8*)&Wc[(kk * 4 + lk) * 256 + (wcc + l15) * 8];
#pragma unroll
                for (int m = 0; m < 4; ++m) {
                    short8 afr = *(const short8*)&Al[buf][lk * 1024 + (wr + m * 16 + l15) * 8];
                    acc[m] = MFMA16(afr, bfr, acc[m]);
                }
                __syncthreads();
            }
            const int j = c0 + wcc + l15;
#pragma unroll
            for (int m = 0; m < 4; ++m)
#pragma unroll
                for (int q = 0; q < 4; ++q)
                    giw[(size_t)(wr + lk * 4 + m * 16 + q) * 1536 + j] = acc[m][q];
        }
        GRIDBAR(bar, DEC_NB);
        // -- Phase D: gate
        for (int i = blk * 256 + tid; i < 65536; i += DEC_NB * 256) {
            int b = i >> 9, u = i & 511;
            const float* ge = gie + ((size_t)t * BATCH + b) * 1536;
            const float* gw = giw + (size_t)b * 1536;
            const float* gH = ghd + (size_t)b * 1536;
            float rr = sigm(ge[u] + gw[u] + gH[u]);
            float zz = sigm(ge[512 + u] + gw[512 + u] + gH[512 + u]);
            float nn = tanhf(ge[1024 + u] + gw[1024 + u] + rr * gH[1024 + u]);
            float h2 = (1.f - zz) * nn + zz * hin[i];
            hout[i] = h2;
            hbout[i] = f2b(h2);
            Xb[((size_t)t * BATCH + b) * XDIM + u] = f2b(h2);
        }
        GRIDBAR(bar, DEC_NB);
    }
}

// ------------------------------------------- in-place log-softmax (V=32000)
__global__ __launch_bounds__(256) void log_softmax_rows(float* __restrict__ data) {
    __shared__ float sm[256], ss[256];
    const size_t row = blockIdx.x;
    float* p = data + row * VOCAB;
    float4* p4 = (float4*)p;
    const int tid = threadIdx.x;
    float m = -3.4e38f, ssum = 0.f;
    for (int i = tid; i < 8000; i += 256) {
        float4 v = p4[i];
        float mx = fmaxf(fmaxf(v.x, v.y), fmaxf(v.z, v.w));
        float mn = fmaxf(m, mx);
        ssum = ssum * expf(m - mn) + expf(v.x - mn) + expf(v.y - mn)
             + expf(v.z - mn) + expf(v.w - mn);
        m = mn;
    }
    sm[tid] = m; ss[tid] = ssum;
    __syncthreads();
    for (int off = 128; off > 0; off >>= 1) {
        if (tid < off) {
            float m2 = sm[tid + off], s2 = ss[tid + off];
            float M = fmaxf(sm[tid], m2);
            ss[tid] = ss[tid] * expf(sm[tid] - M) + s2 * expf(m2 - M);
            sm[tid] = M;
        }
        __syncthreads();
    }
    const float lse = sm[0] + logf(ss[0]);
    for (int i = tid; i < 8000; i += 256) {
        float4 v = p4[i];
        v.x -= lse; v.y -= lse; v.z -= lse; v.w -= lse;
        p4[i] = v;
    }
}

__global__ void fill_last(float* __restrict__ out) {
    int i = blockIdx.x * 256 + threadIdx.x;
    if (i >= BATCH * VOCAB) return;
    int v = i % VOCAB;
    out[(size_t)(T_LEN - 1) * BATCH * VOCAB + i] = (v == 2) ? 100.f : 0.f;
}

// ==================================================================== launch
extern "C" void kernel_launch(void* const* d_in, const int* in_sizes, int n_in,
                              void* d_out, int out_size, void* d_ws, size_t ws_size,
                              hipStream_t stream)
{
    const int*   src     = (const int*)d_in[0];
    const int*   trg     = (const int*)d_in[2];
    const float* emb_enc = (const float*)d_in[3];
    const float* emb_dec = (const float*)d_in[4];
    const float* Wih_f   = (const float*)d_in[5];
    const float* Whh_f   = (const float*)d_in[6];
    const float* bih_f   = (const float*)d_in[7];
    const float* bhh_f   = (const float*)d_in[8];
    const float* Wih_b   = (const float*)d_in[9];
    const float* Whh_b   = (const float*)d_in[10];
    const float* bih_b   = (const float*)d_in[11];
    const float* bhh_b   = (const float*)d_in[12];
    const float* W_fc    = (const float*)d_in[13];
    const float* b_fc    = (const float*)d_in[14];
    const float* W_attn  = (const float*)d_in[15];
    const float* b_attn  = (const float*)d_in[16];
    const float* v_attn  = (const float*)d_in[17];
    const float* Wih_d   = (const float*)d_in[18];
    const float* Whh_d   = (const float*)d_in[19];
    const float* bih_d   = (const float*)d_in[20];
    const float* bhh_d   = (const float*)d_in[21];
    const float* W_out   = (const float*)d_in[22];
    const float* b_out   = (const float*)d_in[23];
    float* out = (float*)d_out;

    char* wsb = (char*)d_ws;
    size_t off = 0;
    auto alloc = [&](size_t bytes) { void* q = wsb + off; off = (off + bytes + 255) & ~(size_t)255; return q; };
    bfu*   emb_b   = (bfu*)alloc((size_t)8192 * 256 * 2);
    bfu*   encbt_b = (bfu*)alloc((size_t)8192 * 1024 * 2);
    float* encp    = (float*)alloc((size_t)8192 * 512 * 4);
    float* gi_f    = (float*)alloc((size_t)8192 * 1536 * 4);
    float* gi_b    = (float*)alloc((size_t)8192 * 1536 * 4);
    float* gie     = (float*)alloc((size_t)3968 * 1536 * 4);
    float* ghE     = (float*)alloc((size_t)2 * 128 * 1536 * 4);
    float* hpb     = (float*)alloc((size_t)128 * 512 * 4);
    bfu*   wbuf    = (bfu*)alloc((size_t)128 * 1024 * 2);
    float* ghd     = (float*)alloc((size_t)128 * 1536 * 4);
    float* giw     = (float*)alloc((size_t)128 * 1536 * 4);
    float* hA      = (float*)alloc((size_t)128 * 1024 * 4);
    float* hB      = (float*)alloc((size_t)128 * 1024 * 4);
    bfu*   hbA     = (bfu*)alloc((size_t)128 * 1024 * 2);
    bfu*   hbB     = (bfu*)alloc((size_t)128 * 1024 * 2);
    float* hdA     = (float*)alloc((size_t)128 * 512 * 4);
    float* hdB     = (float*)alloc((size_t)128 * 512 * 4);
    bfu*   hdbA    = (bfu*)alloc((size_t)128 * 512 * 2);
    bfu*   hdbB    = (bfu*)alloc((size_t)128 * 512 * 2);
    bfu*   Xb      = (bfu*)alloc((size_t)MPAD * XDIM * 2);
    float* barp    = (float*)alloc(256);
    bfu*   Wihf_b  = (bfu*)alloc((size_t)1536 * 256 * 2);
    bfu*   Wihb_b  = (bfu*)alloc((size_t)1536 * 256 * 2);
    bfu*   Whhf_b  = (bfu*)alloc((size_t)1536 * 512 * 2);
    bfu*   Whhb_b  = (bfu*)alloc((size_t)1536 * 512 * 2);
    bfu*   Wfc_b   = (bfu*)alloc((size_t)512 * 1024 * 2);
    bfu*   Wattn_b = (bfu*)alloc((size_t)512 * 1536 * 2);
    bfu*   Wihd_b  = (bfu*)alloc((size_t)1536 * 1280 * 2);
    bfu*   Whhd_b  = (bfu*)alloc((size_t)1536 * 512 * 2);
    bfu*   Wout_b  = (bfu*)alloc((size_t)VOCAB * XDIM * 2);

    auto conv = [&](const float* in, bfu* o, size_t n) {
        conv_f2b<<<(int)((n / 4 + 255) / 256), 256, 0, stream>>>(in, o, (int)(n / 4));
    };
    conv(Wih_f, Wihf_b, 1536 * 256);
    conv(Wih_b, Wihb_b, 1536 * 256);
    conv(Whh_f, Whhf_b, 1536 * 512);
    conv(Whh_b, Whhb_b, 1536 * 512);
    conv(W_fc,  Wfc_b,  512 * 1024);
    conv(W_attn, Wattn_b, 512 * 1536);
    conv(Wih_d, Wihd_b, 1536 * 1280);
    conv(Whh_d, Whhd_b, 1536 * 512);
    conv(W_out, Wout_b, (size_t)VOCAB * XDIM);

    gather_emb<<<(8192 * 256 + 255) / 256, 256, 0, stream>>>(emb_enc, src, emb_b, 8192 * 256);
    gather_trg<<<(3968 * 256 + 255) / 256, 256, 0, stream>>>(emb_dec, trg, Xb, 3968 * 256);
    zero_kernel<<<(131072 + 255) / 256, 256, 0, stream>>>(hA, 131072);
    zero_kernel<<<(65536 + 255) / 256, 256, 0, stream>>>((float*)hbA, 65536);
    zero_kernel<<<1, 256, 0, stream>>>(barp, 64);

    // gi for all encoder steps, both dirs
    gemm_bf16<<<dim3(12, 64, 2), 256, 0, stream>>>(
        emb_b, 256, Wihf_b, 256, gi_f, 1536, bih_f, 256,
        emb_b, 256, Wihb_b, 256, gi_b, 1536, bih_b, 256, 0, nullptr);
    // gi_e for all decoder steps
    gemm_bf16<<<dim3(12, 31, 1), 256, 0, stream>>>(
        Xb + 1536, XDIM, Wihd_b, 1280, gie, 1536, bih_d, 256,
        Xb + 1536, XDIM, Wihd_b, 1280, gie, 1536, bih_d, 256, 0, nullptr);

    // encoder: one persistent launch (64 steps)
    enc_persistent<<<ENC_NB, 256, 0, stream>>>(
        gi_f, gi_b, Whhf_b, Whhb_b, bhh_f, bhh_b,
        hA, hB, hbA, hbB, ghE, encbt_b, (unsigned*)barp);

    // hid = tanh([hf,hb] @ W_fc^T + b_fc)
    gemm_bf16<<<dim3(4, 1, 1), 256, 0, stream>>>(
        hbA, 1024, Wfc_b, 1024, hdA, 512, b_fc, 1024,
        hbA, 1024, Wfc_b, 1024, hdA, 512, b_fc, 1024, 1, hdbA);
    // enc_proj
    gemm_bf16<<<dim3(4, 64, 1), 256, 0, stream>>>(
        encbt_b, 1024, Wattn_b + 512, 1536, encp, 512, b_attn, 1024,
        encbt_b, 1024, Wattn_b + 512, 1536, encp, 512, b_attn, 1024, 0, nullptr);

    // decoder: one persistent launch (31 steps)
    dec_persistent<<<DEC_NB, 256, 0, stream>>>(
        gie, Wattn_b, Whhd_b, Wihd_b, bhh_d, encp, encbt_b, v_attn, src,
        hdA, hdB, hdbA, hdbB, hpb, wbuf, ghd, giw, Xb, (unsigned*)barp + 16);

    // logits + log-softmax + last plane
    gemm_big<<<dim3(125, 16), 512, 0, stream>>>(Xb, Wout_b, out, b_out);
    log_softmax_rows<<<3968, 256, 0, stream>>>(out);
    fill_last<<<(BATCH * VOCAB + 255) / 256, 256, 0, stream>>>(out);
}

// Round 4
// 5865.231 us; speedup vs baseline: 1.7534x; 1.7534x over previous
//
#include <hip/hip_runtime.h>
#include <cstddef>
#include <cstdint>

#define S_LEN 64
#define BATCH 128
#define T_LEN 32
#define E_DIM 256
#define VOCAB 32000
#define XDIM 1792
#define MPAD 4096

typedef unsigned short bfu;
typedef short short8 __attribute__((ext_vector_type(8)));
typedef float f32x4 __attribute__((ext_vector_type(4)));

__device__ __forceinline__ float sigm(float x) { return 1.f / (1.f + expf(-x)); }
__device__ __forceinline__ bfu f2b(float f) {
    unsigned int x = __float_as_uint(f);
    x += 0x7fffu + ((x >> 16) & 1u);
    return (bfu)(x >> 16);
}
__device__ __forceinline__ float b2f(bfu u) { return __uint_as_float(((unsigned)u) << 16); }
__device__ __forceinline__ f32x4 MFMA16(short8 a, short8 b, f32x4 c) {
    return __builtin_amdgcn_mfma_f32_16x16x32_bf16(a, b, c, 0, 0, 0);
}

#define GLDS(gsrc, ldst)                                                       \
    __builtin_amdgcn_global_load_lds(                                          \
        (const __attribute__((address_space(1))) void*)(gsrc),                 \
        (__attribute__((address_space(3))) void*)(ldst), 16, 0, 0)

// ---------------------------------------------------------------- utilities
__global__ void zero_kernel(float* __restrict__ p, int n) {
    int i = blockIdx.x * 256 + threadIdx.x;
    if (i < n) p[i] = 0.f;
}

__global__ void conv_f2b(const float* __restrict__ in, bfu* __restrict__ out, int n4) {
    int i = blockIdx.x * 256 + threadIdx.x;
    if (i >= n4) return;
    float4 v = ((const float4*)in)[i];
    ushort4 o;
    o.x = f2b(v.x); o.y = f2b(v.y); o.z = f2b(v.z); o.w = f2b(v.w);
    ((ushort4*)out)[i] = o;
}

__global__ void gather_emb(const float* __restrict__ table, const int* __restrict__ idx,
                           bfu* __restrict__ out, int total) {
    int i = blockIdx.x * 256 + threadIdx.x;
    if (i >= total) return;
    int row = i >> 8, k = i & 255;
    out[i] = f2b(table[(size_t)idx[row] * E_DIM + k]);
}

__global__ void gather_trg(const float* __restrict__ table, const int* __restrict__ trg,
                           bfu* __restrict__ Xb, int total) {
    int i = blockIdx.x * 256 + threadIdx.x;
    if (i >= total) return;
    int row = i >> 8, k = i & 255;
    Xb[(size_t)row * XDIM + 1536 + k] = f2b(table[(size_t)trg[row] * E_DIM + k]);
}

// ----------------------------------------------- generic bf16 MFMA GEMM (NT)
// (verified) BM=BN=128, BK=32; 256 thr = 4 waves 2x2, wave tile 64x64
__global__ __launch_bounds__(256) void gemm_bf16(
    const bfu* __restrict__ A0, int lda0, const bfu* __restrict__ W0, int ldw0,
    float* __restrict__ C0, int ldc0, const float* __restrict__ bias0, int K0,
    const bfu* __restrict__ A1, int lda1, const bfu* __restrict__ W1, int ldw1,
    float* __restrict__ C1, int ldc1, const float* __restrict__ bias1, int K1,
    int act, bfu* __restrict__ Cb0)
{
    const int z = blockIdx.z;
    const bfu* A = z ? A1 : A0;
    const bfu* W = z ? W1 : W0;
    float*     C = z ? C1 : C0;
    const float* bias = z ? bias1 : bias0;
    bfu*       Cb = z ? nullptr : Cb0;
    const int lda = z ? lda1 : lda0;
    const int ldw = z ? ldw1 : ldw0;
    const int ldc = z ? ldc1 : ldc0;
    const int K   = z ? K1 : K0;

    __shared__ short lds[2][2][4096];
    const int tid  = threadIdx.x;
    const int wid  = tid >> 6, lane = tid & 63;
    const int l15  = lane & 15, lk = lane >> 4;
    const int wr   = (wid >> 1) * 64, wc = (wid & 1) * 64;
    const size_t row0 = (size_t)blockIdx.y * 128;
    const size_t col0 = (size_t)blockIdx.x * 128;

    const int c0 = tid, c1 = tid + 256;
    const int r0 = c0 & 127, kc0 = c0 >> 7;
    const int r1 = c1 & 127, kc1 = c1 >> 7;
    const int sb0 = (wid * 64) * 16;
    const int sb1 = (wid * 64 + 256) * 16;

    f32x4 acc[4][4];
#pragma unroll
    for (int m = 0; m < 4; ++m)
#pragma unroll
        for (int n = 0; n < 4; ++n) acc[m][n] = (f32x4){0.f, 0.f, 0.f, 0.f};

    auto stage = [&](int buf, int kt) {
        char* ba = (char*)&lds[buf][0][0];
        char* bb = (char*)&lds[buf][1][0];
        GLDS(A + (row0 + r0) * (size_t)lda + kt + kc0 * 8, ba + sb0);
        GLDS(A + (row0 + r1) * (size_t)lda + kt + kc1 * 8, ba + sb1);
        GLDS(W + (col0 + r0) * (size_t)ldw + kt + kc0 * 8, bb + sb0);
        GLDS(W + (col0 + r1) * (size_t)ldw + kt + kc1 * 8, bb + sb1);
    };

    stage(0, 0);
    __syncthreads();
    const int nk = K >> 5;
    for (int t = 0; t < nk; ++t) {
        const int buf = t & 1;
        if (t + 1 < nk) stage(buf ^ 1, (t + 1) << 5);
        short8 af[4], bf_[4];
#pragma unroll
        for (int m = 0; m < 4; ++m)
            af[m] = *(const short8*)&lds[buf][0][lk * 1024 + (wr + m * 16 + l15) * 8];
#pragma unroll
        for (int n = 0; n < 4; ++n)
            bf_[n] = *(const short8*)&lds[buf][1][lk * 1024 + (wc + n * 16 + l15) * 8];
#pragma unroll
        for (int m = 0; m < 4; ++m)
#pragma unroll
            for (int n = 0; n < 4; ++n)
                acc[m][n] = MFMA16(af[m], bf_[n], acc[m][n]);
        __syncthreads();
    }

    float bv[4];
#pragma unroll
    for (int n = 0; n < 4; ++n)
        bv[n] = bias ? bias[col0 + wc + n * 16 + l15] : 0.f;
    const size_t crow = row0 + wr + lk * 4;
#pragma unroll
    for (int m = 0; m < 4; ++m) {
#pragma unroll
        for (int q = 0; q < 4; ++q) {
            const size_t r = crow + m * 16 + q;
            float* cp = C + r * ldc + col0 + wc + l15;
            bfu*   cb = Cb ? (Cb + r * ldc + col0 + wc + l15) : nullptr;
#pragma unroll
            for (int n = 0; n < 4; ++n) {
                float v = acc[m][n][q] + bv[n];
                if (act) v = tanhf(v);
                cp[n * 16] = v;
                if (Cb) cb[n * 16] = f2b(v);
            }
        }
    }
}

// ----------------------------------------------- big output GEMM, 256x256 tile
__global__ __launch_bounds__(512) void gemm_big(
    const bfu* __restrict__ A, const bfu* __restrict__ W,
    float* __restrict__ C, const float* __restrict__ bias)
{
    __shared__ short lds[2][2][8192];
    const int tid = threadIdx.x;
    const int wid = tid >> 6, lane = tid & 63;
    const int l15 = lane & 15, lk = lane >> 4;
    const int wr = (wid >> 2) * 128;
    const int wcc = (wid & 3) * 64;
    const int fid  = blockIdx.y * 125 + blockIdx.x;       // 2000 = 8*250
    const int fid2 = (fid & 7) * 250 + (fid >> 3);
    const int bx = fid2 / 16, by = fid2 % 16;
    const size_t row0 = (size_t)by * 256;
    const size_t col0 = (size_t)bx * 256;

    f32x4 acc[8][4];
#pragma unroll
    for (int m = 0; m < 8; ++m)
#pragma unroll
        for (int n = 0; n < 4; ++n) acc[m][n] = (f32x4){0.f, 0.f, 0.f, 0.f};

    auto stage = [&](int buf, int kt) {
        char* ba = (char*)&lds[buf][0][0];
        char* bb = (char*)&lds[buf][1][0];
#pragma unroll
        for (int it = 0; it < 2; ++it) {
            int c = it * 512 + tid;
            int kc = c >> 8, row = c & 255;
            int base = (it * 512 + wid * 64) * 16;
            GLDS(A + (row0 + row) * (size_t)XDIM + kt + kc * 8, ba + base);
            GLDS(W + (col0 + row) * (size_t)XDIM + kt + kc * 8, bb + base);
        }
    };

    stage(0, 0);
    __syncthreads();
    for (int t = 0; t < 56; ++t) {
        const int buf = t & 1;
        if (t < 55) stage(buf ^ 1, (t + 1) * 32);
        short8 af[8], bf_[4];
#pragma unroll
        for (int m = 0; m < 8; ++m)
            af[m] = *(const short8*)&lds[buf][0][lk * 2048 + (wr + m * 16 + l15) * 8];
#pragma unroll
        for (int n = 0; n < 4; ++n)
            bf_[n] = *(const short8*)&lds[buf][1][lk * 2048 + (wcc + n * 16 + l15) * 8];
#pragma unroll
        for (int m = 0; m < 8; ++m)
#pragma unroll
            for (int n = 0; n < 4; ++n)
                acc[m][n] = MFMA16(af[m], bf_[n], acc[m][n]);
        __syncthreads();
    }
    if (row0 + wr < 3968) {
        float bv[4];
#pragma unroll
        for (int n = 0; n < 4; ++n) bv[n] = bias[col0 + wcc + n * 16 + l15];
#pragma unroll
        for (int m = 0; m < 8; ++m) {
#pragma unroll
            for (int q = 0; q < 4; ++q) {
                const size_t r = row0 + wr + lk * 4 + m * 16 + q;
                float* cp = C + r * VOCAB + col0 + wcc + l15;
#pragma unroll
                for (int n = 0; n < 4; ++n) cp[n * 16] = acc[m][n][q] + bv[n];
            }
        }
    }
}

// ----------------------------------------------- fused encoder step
// grid (16 u-slices, 1, 2 dirs), 256 thr. Block computes gh rows {u,512+u,1024+u}
// for its 32-unit slice as one 128x96 MFMA tile (K=512), gate in-register.
__global__ __launch_bounds__(256) void enc_step(
    const float* __restrict__ gi_f, const float* __restrict__ gi_b,
    const bfu* __restrict__ Whhf_b, const bfu* __restrict__ Whhb_b,
    const float* __restrict__ bhh_f, const float* __restrict__ bhh_b,
    const float* __restrict__ hin, float* __restrict__ hout,
    const bfu* __restrict__ hbin, bfu* __restrict__ hbout,
    bfu* __restrict__ encbt, int s)
{
    __shared__ short Asl[2][4096];   // [kc4][128][8]
    __shared__ short Wsl[2][3072];   // [kc4][96][8]
    const int tid = threadIdx.x;
    const int wid = tid >> 6, lane = tid & 63;
    const int l15 = lane & 15, lk = lane >> 4;
    const int dir = blockIdx.z;
    const int u0 = blockIdx.x * 32;
    const int p = dir ? (S_LEN - 1 - s) : s;
    const bfu* Whh = dir ? Whhb_b : Whhf_b;
    const float* bhh = dir ? bhh_b : bhh_f;
    const float* gi = (dir ? gi_b : gi_f) + (size_t)p * BATCH * 1536;

    // thread-constant staging coords
    const int a_r0 = tid & 127, a_k0 = tid >> 7;
    const int a_k1 = a_k0 + 2;
    const int w_r0 = tid % 96,  w_k0 = tid / 96;
    const int w_r1 = (tid + 256) % 96, w_k1 = (tid + 256) / 96;
    auto wrow = [&](int r96) {
        return r96 < 32 ? (u0 + r96) : r96 < 64 ? (512 + u0 + r96 - 32)
                                                : (1024 + u0 + r96 - 64);
    };
    const int wro0 = wrow(w_r0), wro1 = wrow(w_r1);

    f32x4 acc[2][6];
#pragma unroll
    for (int m = 0; m < 2; ++m)
#pragma unroll
        for (int n = 0; n < 6; ++n) acc[m][n] = (f32x4){0.f, 0.f, 0.f, 0.f};

    auto stage = [&](int buf, int kt) {
        char* ba = (char*)&Asl[buf][0];
        char* bw = (char*)&Wsl[buf][0];
        GLDS(hbin + (size_t)a_r0 * 1024 + dir * 512 + kt + a_k0 * 8, ba + (wid * 64) * 16);
        GLDS(hbin + (size_t)a_r0 * 1024 + dir * 512 + kt + a_k1 * 8, ba + (256 + wid * 64) * 16);
        GLDS(Whh + (size_t)wro0 * 512 + kt + w_k0 * 8, bw + (wid * 64) * 16);
        if (tid < 128)
            GLDS(Whh + (size_t)wro1 * 512 + kt + w_k1 * 8, bw + (256 + wid * 64) * 16);
    };

    stage(0, 0);
    __syncthreads();
    for (int kk = 0; kk < 16; ++kk) {
        const int buf = kk & 1;
        if (kk < 15) stage(buf ^ 1, (kk + 1) * 32);
        short8 af[2], bf_[6];
#pragma unroll
        for (int m = 0; m < 2; ++m)
            af[m] = *(const short8*)&Asl[buf][(lk * 128 + wid * 32 + m * 16 + l15) * 8];
#pragma unroll
        for (int n = 0; n < 6; ++n)
            bf_[n] = *(const short8*)&Wsl[buf][(lk * 96 + n * 16 + l15) * 8];
#pragma unroll
        for (int m = 0; m < 2; ++m)
#pragma unroll
            for (int n = 0; n < 6; ++n)
                acc[m][n] = MFMA16(af[m], bf_[n], acc[m][n]);
        __syncthreads();
    }

    // in-register gate
#pragma unroll
    for (int m = 0; m < 2; ++m) {
#pragma unroll
        for (int q = 0; q < 4; ++q) {
            const int b = wid * 32 + m * 16 + lk * 4 + q;
            const float* gib = gi + (size_t)b * 1536;
#pragma unroll
            for (int j = 0; j < 2; ++j) {
                const int u = u0 + j * 16 + l15;
                float rr = sigm(gib[u] + acc[m][j][q] + bhh[u]);
                float zz = sigm(gib[512 + u] + acc[m][2 + j][q] + bhh[512 + u]);
                float nn = tanhf(gib[1024 + u] + rr * (acc[m][4 + j][q] + bhh[1024 + u]));
                float h2 = (1.f - zz) * nn + zz * hin[(size_t)b * 1024 + dir * 512 + u];
                hout[(size_t)b * 1024 + dir * 512 + u] = h2;
                hbout[(size_t)b * 1024 + dir * 512 + u] = f2b(h2);
                encbt[((size_t)b * S_LEN + p) * 1024 + dir * 512 + u] = f2b(h2);
            }
        }
    }
}

// ----------------------------------------------- fused hp + attention step
__global__ __launch_bounds__(256) void attn_fused(
    const bfu* __restrict__ hb, const bfu* __restrict__ Wahb,
    const float* __restrict__ encp, const bfu* __restrict__ encbt,
    const float* __restrict__ v_attn, const int* __restrict__ src,
    bfu* __restrict__ wbuf, bfu* __restrict__ Xb, int t)
{
    __shared__ float hls[512];
    __shared__ float vas[512];
    __shared__ float hps[512];
    __shared__ float sc[64];
    const int b = blockIdx.x, tid = threadIdx.x;
    for (int i = tid; i < 512; i += 256) {
        hls[i] = b2f(hb[(size_t)b * 512 + i]);
        vas[i] = v_attn[i];
    }
    __syncthreads();
    for (int j = tid; j < 512; j += 256) {
        const uint4* wrow = (const uint4*)(Wahb + (size_t)j * 1536);
        float acc = 0.f;
#pragma unroll 8
        for (int k8 = 0; k8 < 64; ++k8) {
            uint4 wv = wrow[k8];
            const float* xp = &hls[k8 * 8];
            acc += __uint_as_float(wv.x << 16) * xp[0] + __uint_as_float(wv.x & 0xffff0000u) * xp[1]
                 + __uint_as_float(wv.y << 16) * xp[2] + __uint_as_float(wv.y & 0xffff0000u) * xp[3]
                 + __uint_as_float(wv.z << 16) * xp[4] + __uint_as_float(wv.z & 0xffff0000u) * xp[5]
                 + __uint_as_float(wv.w << 16) * xp[6] + __uint_as_float(wv.w & 0xffff0000u) * xp[7];
        }
        hps[j] = acc;
    }
    __syncthreads();
    const int s = tid >> 2, l4 = tid & 3;
    const float* ep = encp + ((size_t)b * S_LEN + s) * 512;
    float part = 0.f;
#pragma unroll 4
    for (int d = l4; d < 512; d += 4) part += vas[d] * tanhf(ep[d] + hps[d]);
    part += __shfl_xor(part, 1);
    part += __shfl_xor(part, 2);
    if (l4 == 0) sc[s] = (src[s * BATCH + b] != 0) ? part : -1e10f;
    __syncthreads();
    if (tid < 64) {
        float x = sc[tid], mx = x;
        for (int o = 1; o < 64; o <<= 1) mx = fmaxf(mx, __shfl_xor(mx, o));
        float e = expf(x - mx), s2 = e;
        for (int o = 1; o < 64; o <<= 1) s2 += __shfl_xor(s2, o);
        sc[tid] = e / s2;
    }
    __syncthreads();
    bfu* xw = Xb + ((size_t)t * BATCH + b) * XDIM + 512;
#pragma unroll
    for (int c = 0; c < 4; ++c) {
        int e = tid + 256 * c;
        float a2 = 0.f;
#pragma unroll 8
        for (int s2 = 0; s2 < S_LEN; ++s2) a2 += sc[s2] * b2f(encbt[((size_t)b * S_LEN + s2) * 1024 + e]);
        bfu v = f2b(a2);
        wbuf[(size_t)b * 1024 + e] = v;
        xw[e] = v;
    }
}

// ----------------------------------------------- fused decoder GEMM + gate
// grid 16 u-slices, 256 thr. acc_h = h@Whhd^T (K=512); acc_w = w@Wihd_w^T (K=1024)
__global__ __launch_bounds__(256) void dec_step_gemm(
    const float* __restrict__ gie, const bfu* __restrict__ Whhd_b,
    const bfu* __restrict__ Wihd_b, const float* __restrict__ bhh_d,
    const bfu* __restrict__ hbin, const bfu* __restrict__ wbuf,
    const float* __restrict__ hin, float* __restrict__ hout,
    bfu* __restrict__ hbout, bfu* __restrict__ Xb, int t)
{
    __shared__ short Asl[2][4096];
    __shared__ short Wsl[2][3072];
    const int tid = threadIdx.x;
    const int wid = tid >> 6, lane = tid & 63;
    const int l15 = lane & 15, lk = lane >> 4;
    const int u0 = blockIdx.x * 32;

    const int a_r0 = tid & 127, a_k0 = tid >> 7;
    const int a_k1 = a_k0 + 2;
    const int w_r0 = tid % 96,  w_k0 = tid / 96;
    const int w_r1 = (tid + 256) % 96, w_k1 = (tid + 256) / 96;
    auto wrow = [&](int r96) {
        return r96 < 32 ? (u0 + r96) : r96 < 64 ? (512 + u0 + r96 - 32)
                                                : (1024 + u0 + r96 - 64);
    };
    const int wro0 = wrow(w_r0), wro1 = wrow(w_r1);

    f32x4 acc_h[2][6], acc_w[2][6];
#pragma unroll
    for (int m = 0; m < 2; ++m)
#pragma unroll
        for (int n = 0; n < 6; ++n) {
            acc_h[m][n] = (f32x4){0.f, 0.f, 0.f, 0.f};
            acc_w[m][n] = (f32x4){0.f, 0.f, 0.f, 0.f};
        }

    // ---- loop 1: acc_h over hbin [128][512] x Whhd rows
    auto stage1 = [&](int buf, int kt) {
        char* ba = (char*)&Asl[buf][0];
        char* bw = (char*)&Wsl[buf][0];
        GLDS(hbin + (size_t)a_r0 * 512 + kt + a_k0 * 8, ba + (wid * 64) * 16);
        GLDS(hbin + (size_t)a_r0 * 512 + kt + a_k1 * 8, ba + (256 + wid * 64) * 16);
        GLDS(Whhd_b + (size_t)wro0 * 512 + kt + w_k0 * 8, bw + (wid * 64) * 16);
        if (tid < 128)
            GLDS(Whhd_b + (size_t)wro1 * 512 + kt + w_k1 * 8, bw + (256 + wid * 64) * 16);
    };
    stage1(0, 0);
    __syncthreads();
    for (int kk = 0; kk < 16; ++kk) {
        const int buf = kk & 1;
        if (kk < 15) stage1(buf ^ 1, (kk + 1) * 32);
        short8 af[2], bf_[6];
#pragma unroll
        for (int m = 0; m < 2; ++m)
            af[m] = *(const short8*)&Asl[buf][(lk * 128 + wid * 32 + m * 16 + l15) * 8];
#pragma unroll
        for (int n = 0; n < 6; ++n)
            bf_[n] = *(const short8*)&Wsl[buf][(lk * 96 + n * 16 + l15) * 8];
#pragma unroll
        for (int m = 0; m < 2; ++m)
#pragma unroll
            for (int n = 0; n < 6; ++n)
                acc_h[m][n] = MFMA16(af[m], bf_[n], acc_h[m][n]);
        __syncthreads();
    }

    // ---- loop 2: acc_w over wbuf [128][1024] x Wihd cols 256..1279
    auto stage2 = [&](int buf, int kt) {
        char* ba = (char*)&Asl[buf][0];
        char* bw = (char*)&Wsl[buf][0];
        GLDS(wbuf + (size_t)a_r0 * 1024 + kt + a_k0 * 8, ba + (wid * 64) * 16);
        GLDS(wbuf + (size_t)a_r0 * 1024 + kt + a_k1 * 8, ba + (256 + wid * 64) * 16);
        GLDS(Wihd_b + (size_t)wro0 * 1280 + 256 + kt + w_k0 * 8, bw + (wid * 64) * 16);
        if (tid < 128)
            GLDS(Wihd_b + (size_t)wro1 * 1280 + 256 + kt + w_k1 * 8, bw + (256 + wid * 64) * 16);
    };
    stage2(0, 0);
    __syncthreads();
    for (int kk = 0; kk < 32; ++kk) {
        const int buf = kk & 1;
        if (kk < 31) stage2(buf ^ 1, (kk + 1) * 32);
        short8 af[2], bf_[6];
#pragma unroll
        for (int m = 0; m < 2; ++m)
            af[m] = *(const short8*)&Asl[buf][(lk * 128 + wid * 32 + m * 16 + l15) * 8];
#pragma unroll
        for (int n = 0; n < 6; ++n)
            bf_[n] = *(const short8*)&Wsl[buf][(lk * 96 + n * 16 + l15) * 8];
#pragma unroll
        for (int m = 0; m < 2; ++m)
#pragma unroll
            for (int n = 0; n < 6; ++n)
                acc_w[m][n] = MFMA16(af[m], bf_[n], acc_w[m][n]);
        __syncthreads();
    }

    // ---- in-register gate
#pragma unroll
    for (int m = 0; m < 2; ++m) {
#pragma unroll
        for (int q = 0; q < 4; ++q) {
            const int b = wid * 32 + m * 16 + lk * 4 + q;
            const float* geb = gie + ((size_t)t * BATCH + b) * 1536;
#pragma unroll
            for (int j = 0; j < 2; ++j) {
                const int u = u0 + j * 16 + l15;
                float gH_r = acc_h[m][j][q] + bhh_d[u];
                float gH_z = acc_h[m][2 + j][q] + bhh_d[512 + u];
                float gH_n = acc_h[m][4 + j][q] + bhh_d[1024 + u];
                float rr = sigm(geb[u] + acc_w[m][j][q] + gH_r);
                float zz = sigm(geb[512 + u] + acc_w[m][2 + j][q] + gH_z);
                float nn = tanhf(geb[1024 + u] + acc_w[m][4 + j][q] + rr * gH_n);
                float h2 = (1.f - zz) * nn + zz * hin[(size_t)b * 512 + u];
                hout[(size_t)b * 512 + u] = h2;
                hbout[(size_t)b * 512 + u] = f2b(h2);
                Xb[((size_t)t * BATCH + b) * XDIM + u] = f2b(h2);
            }
        }
    }
}

// ------------------------------------------- in-place log-softmax (V=32000)
__global__ __launch_bounds__(256) void log_softmax_rows(float* __restrict__ data) {
    __shared__ float sm[256], ss[256];
    const size_t row = blockIdx.x;
    float* p = data + row * VOCAB;
    float4* p4 = (float4*)p;
    const int tid = threadIdx.x;
    float m = -3.4e38f, ssum = 0.f;
    for (int i = tid; i < 8000; i += 256) {
        float4 v = p4[i];
        float mx = fmaxf(fmaxf(v.x, v.y), fmaxf(v.z, v.w));
        float mn = fmaxf(m, mx);
        ssum = ssum * expf(m - mn) + expf(v.x - mn) + expf(v.y - mn)
             + expf(v.z - mn) + expf(v.w - mn);
        m = mn;
    }
    sm[tid] = m; ss[tid] = ssum;
    __syncthreads();
    for (int off = 128; off > 0; off >>= 1) {
        if (tid < off) {
            float m2 = sm[tid + off], s2 = ss[tid + off];
            float M = fmaxf(sm[tid], m2);
            ss[tid] = ss[tid] * expf(sm[tid] - M) + s2 * expf(m2 - M);
            sm[tid] = M;
        }
        __syncthreads();
    }
    const float lse = sm[0] + logf(ss[0]);
    for (int i = tid; i < 8000; i += 256) {
        float4 v = p4[i];
        v.x -= lse; v.y -= lse; v.z -= lse; v.w -= lse;
        p4[i] = v;
    }
}

__global__ void fill_last(float* __restrict__ out) {
    int i = blockIdx.x * 256 + threadIdx.x;
    if (i >= BATCH * VOCAB) return;
    int v = i % VOCAB;
    out[(size_t)(T_LEN - 1) * BATCH * VOCAB + i] = (v == 2) ? 100.f : 0.f;
}

// ==================================================================== launch
extern "C" void kernel_launch(void* const* d_in, const int* in_sizes, int n_in,
                              void* d_out, int out_size, void* d_ws, size_t ws_size,
                              hipStream_t stream)
{
    const int*   src     = (const int*)d_in[0];
    const int*   trg     = (const int*)d_in[2];
    const float* emb_enc = (const float*)d_in[3];
    const float* emb_dec = (const float*)d_in[4];
    const float* Wih_f   = (const float*)d_in[5];
    const float* Whh_f   = (const float*)d_in[6];
    const float* bih_f   = (const float*)d_in[7];
    const float* bhh_f   = (const float*)d_in[8];
    const float* Wih_b   = (const float*)d_in[9];
    const float* Whh_b   = (const float*)d_in[10];
    const float* bih_b   = (const float*)d_in[11];
    const float* bhh_b   = (const float*)d_in[12];
    const float* W_fc    = (const float*)d_in[13];
    const float* b_fc    = (const float*)d_in[14];
    const float* W_attn  = (const float*)d_in[15];
    const float* b_attn  = (const float*)d_in[16];
    const float* v_attn  = (const float*)d_in[17];
    const float* Wih_d   = (const float*)d_in[18];
    const float* Whh_d   = (const float*)d_in[19];
    const float* bih_d   = (const float*)d_in[20];
    const float* bhh_d   = (const float*)d_in[21];
    const float* W_out   = (const float*)d_in[22];
    const float* b_out   = (const float*)d_in[23];
    float* out = (float*)d_out;

    char* wsb = (char*)d_ws;
    size_t off = 0;
    auto alloc = [&](size_t bytes) { void* q = wsb + off; off = (off + bytes + 255) & ~(size_t)255; return q; };
    bfu*   emb_b   = (bfu*)alloc((size_t)8192 * 256 * 2);
    bfu*   encbt_b = (bfu*)alloc((size_t)8192 * 1024 * 2);
    float* encp    = (float*)alloc((size_t)8192 * 512 * 4);
    float* gi_f    = (float*)alloc((size_t)8192 * 1536 * 4);
    float* gi_b    = (float*)alloc((size_t)8192 * 1536 * 4);
    float* gie     = (float*)alloc((size_t)3968 * 1536 * 4);
    bfu*   wbuf    = (bfu*)alloc((size_t)128 * 1024 * 2);
    float* hA      = (float*)alloc((size_t)128 * 1024 * 4);
    float* hB      = (float*)alloc((size_t)128 * 1024 * 4);
    bfu*   hbA     = (bfu*)alloc((size_t)128 * 1024 * 2);
    bfu*   hbB     = (bfu*)alloc((size_t)128 * 1024 * 2);
    float* hdA     = (float*)alloc((size_t)128 * 512 * 4);
    float* hdB     = (float*)alloc((size_t)128 * 512 * 4);
    bfu*   hdbA    = (bfu*)alloc((size_t)128 * 512 * 2);
    bfu*   hdbB    = (bfu*)alloc((size_t)128 * 512 * 2);
    bfu*   Xb      = (bfu*)alloc((size_t)MPAD * XDIM * 2);
    bfu*   Wihf_b  = (bfu*)alloc((size_t)1536 * 256 * 2);
    bfu*   Wihb_b  = (bfu*)alloc((size_t)1536 * 256 * 2);
    bfu*   Whhf_b  = (bfu*)alloc((size_t)1536 * 512 * 2);
    bfu*   Whhb_b  = (bfu*)alloc((size_t)1536 * 512 * 2);
    bfu*   Wfc_b   = (bfu*)alloc((size_t)512 * 1024 * 2);
    bfu*   Wattn_b = (bfu*)alloc((size_t)512 * 1536 * 2);
    bfu*   Wihd_b  = (bfu*)alloc((size_t)1536 * 1280 * 2);
    bfu*   Whhd_b  = (bfu*)alloc((size_t)1536 * 512 * 2);
    bfu*   Wout_b  = (bfu*)alloc((size_t)VOCAB * XDIM * 2);

    auto conv = [&](const float* in, bfu* o, size_t n) {
        conv_f2b<<<(int)((n / 4 + 255) / 256), 256, 0, stream>>>(in, o, (int)(n / 4));
    };
    conv(Wih_f, Wihf_b, 1536 * 256);
    conv(Wih_b, Wihb_b, 1536 * 256);
    conv(Whh_f, Whhf_b, 1536 * 512);
    conv(Whh_b, Whhb_b, 1536 * 512);
    conv(W_fc,  Wfc_b,  512 * 1024);
    conv(W_attn, Wattn_b, 512 * 1536);
    conv(Wih_d, Wihd_b, 1536 * 1280);
    conv(Whh_d, Whhd_b, 1536 * 512);
    conv(W_out, Wout_b, (size_t)VOCAB * XDIM);

    gather_emb<<<(8192 * 256 + 255) / 256, 256, 0, stream>>>(emb_enc, src, emb_b, 8192 * 256);
    gather_trg<<<(3968 * 256 + 255) / 256, 256, 0, stream>>>(emb_dec, trg, Xb, 3968 * 256);
    zero_kernel<<<(131072 + 255) / 256, 256, 0, stream>>>(hA, 131072);
    zero_kernel<<<(65536 + 255) / 256, 256, 0, stream>>>((float*)hbA, 65536);

    // gi for all encoder steps, both dirs
    gemm_bf16<<<dim3(12, 64, 2), 256, 0, stream>>>(
        emb_b, 256, Wihf_b, 256, gi_f, 1536, bih_f, 256,
        emb_b, 256, Wihb_b, 256, gi_b, 1536, bih_b, 256, 0, nullptr);
    // gi_e for all decoder steps
    gemm_bf16<<<dim3(12, 31, 1), 256, 0, stream>>>(
        Xb + 1536, XDIM, Wihd_b, 1280, gie, 1536, bih_d, 256,
        Xb + 1536, XDIM, Wihd_b, 1280, gie, 1536, bih_d, 256, 0, nullptr);

    // encoder: 64 fused steps (1 launch each)
    for (int s = 0; s < S_LEN; ++s) {
        const float* hin  = (s & 1) ? hB : hA;
        float*       hout = (s & 1) ? hA : hB;
        const bfu*   hbin = (s & 1) ? hbB : hbA;
        bfu*         hbout = (s & 1) ? hbA : hbB;
        enc_step<<<dim3(16, 1, 2), 256, 0, stream>>>(
            gi_f, gi_b, Whhf_b, Whhb_b, bhh_f, bhh_b,
            hin, hout, hbin, hbout, encbt_b, s);
    }
    // hid = tanh([hf,hb] @ W_fc^T + b_fc)   (final enc h in hA/hbA)
    gemm_bf16<<<dim3(4, 1, 1), 256, 0, stream>>>(
        hbA, 1024, Wfc_b, 1024, hdA, 512, b_fc, 1024,
        hbA, 1024, Wfc_b, 1024, hdA, 512, b_fc, 1024, 1, hdbA);
    // enc_proj
    gemm_bf16<<<dim3(4, 64, 1), 256, 0, stream>>>(
        encbt_b, 1024, Wattn_b + 512, 1536, encp, 512, b_attn, 1024,
        encbt_b, 1024, Wattn_b + 512, 1536, encp, 512, b_attn, 1024, 0, nullptr);

    // decoder: 31 steps x 2 launches
    for (int t = 0; t < T_LEN - 1; ++t) {
        const float* hin  = (t & 1) ? hdB : hdA;
        float*       hout = (t & 1) ? hdA : hdB;
        const bfu*   hbin = (t & 1) ? hdbB : hdbA;
        bfu*         hbout = (t & 1) ? hdbA : hdbB;
        attn_fused<<<BATCH, 256, 0, stream>>>(hbin, Wattn_b, encp, encbt_b,
                                              v_attn, src, wbuf, Xb, t);
        dec_step_gemm<<<16, 256, 0, stream>>>(
            gie, Whhd_b, Wihd_b, bhh_d, hbin, wbuf, hin, hout, hbout, Xb, t);
    }

    // logits + log-softmax + last plane
    gemm_big<<<dim3(125, 16), 512, 0, stream>>>(Xb, Wout_b, out, b_out);
    log_softmax_rows<<<3968, 256, 0, stream>>>(out);
    fill_last<<<(BATCH * VOCAB + 255) / 256, 256, 0, stream>>>(out);
}